// Round 4
// baseline (321.693 us; speedup 1.0000x reference)
//
#include <hip/hip_runtime.h>

// Problem constants (from reference)
#define CC 9605
#define BB 2048
#define LL 8
#define NSLOT 41          // 10 float4-groups + 1 head/tail extra per thread
#define CAND_MAX 512
#define NEGF (-1e30f)

// d_ws layout (unsigned words):
//   wsu[0] = wl entry count (atomic)
//   wsu[1] = dtype sniff flags (atomic OR)
//   wsu[2] = loss-block done counter (last block reduces)
//   wsu[4 .. 4+2048) = whitelist entries (col<<8 | mask)
//   byte offset 16384: float partials[BB]
#define WS_PARTIALS_OFF 16384

__device__ __forceinline__ unsigned enc_f(float f) {
  unsigned u = __float_as_uint(f);
  return (u & 0x80000000u) ? ~u : (u | 0x80000000u);
}
__device__ __forceinline__ float dec_u(unsigned e) {
  unsigned u = (e & 0x80000000u) ? (e & 0x7fffffffu) : ~e;
  return __uint_as_float(u);
}
__device__ __forceinline__ float sigm(float z) {
  return 1.0f / (1.0f + __expf(-z));
}

// ---- dtype sniff (word loads): byte signatures over the raw wl buffer ----
//   u8  : byte==1 at offsets %4 != 0        -> flag 1 (and 2)
//   i32 : byte==1 only at offsets %4 == 0   -> flag 2
//   f32 : 0x3f at %4==3, never byte==1      -> flag 8
//   bf16: 0x3f at odd offsets incl %4==1    -> flag 4 (and 8)
__global__ void wl_sniff(const unsigned* __restrict__ wlw,
                         unsigned* __restrict__ wsu) {
  const int nwords = (LL * CC) / 4;  // 76840 % 4 == 0
  const int stride = gridDim.x * blockDim.x;
  unsigned f = 0u;
  for (int j = blockIdx.x * blockDim.x + threadIdx.x; j < nwords; j += stride) {
    unsigned w = wlw[j];
#pragma unroll
    for (int k = 0; k < 4; ++k) {
      unsigned b = (w >> (8 * k)) & 255u;
      if (b == 1u)    { f |= 2u; if (k != 0) f |= 1u; }
      if (b == 0x3fu) { f |= 8u; if (k == 1) f |= 4u; }
    }
  }
#pragma unroll
  for (int off = 32; off >= 1; off >>= 1) f |= __shfl_xor(f, off, 64);
  if ((threadIdx.x & 63) == 0 && f) atomicOr(&wsu[1], f);
}

__global__ void wl_compact(const unsigned char* __restrict__ wl,
                           unsigned* __restrict__ wsu) {
  const int tid = threadIdx.x;
  const int lane = tid & 63;
  const int c = blockIdx.x * 256 + tid;
  const unsigned g = wsu[1];
  const int dt = (g & 1u) ? 0 : (g & 4u) ? 3 : (g & 2u) ? 1 : (g & 8u) ? 2 : 0;
  const int* wl32 = (const int*)wl;
  const float* wlf = (const float*)wl;
  const unsigned short* wlh = (const unsigned short*)wl;
  unsigned m = 0u;
  if (c < CC) {
#pragma unroll
    for (int l = 0; l < LL; ++l) {
      int j = l * CC + c;
      bool on;
      if (dt == 0) on = (wl[j] != 0);
      else if (dt == 1) on = (wl32[j] != 0);
      else if (dt == 2) on = (wlf[j] != 0.0f);
      else on = (wlh[j] != 0);
      if (on) m |= (1u << l);
    }
  }
  unsigned long long bal = __ballot(m != 0u);
  if (bal) {
    unsigned wcnt = (unsigned)__popcll(bal);
    unsigned basep = 0u;
    if (lane == 0) basep = atomicAdd(&wsu[0], wcnt);
    basep = __shfl(basep, 0, 64);
    if (m) {
      unsigned pos = basep + (unsigned)__popcll(bal & ((1ull << lane) - 1ull));
      if (pos < 2048u) wsu[4 + pos] = ((unsigned)c << 8) | m;
    }
  }
}

__global__ __launch_bounds__(256, 4) void loss_kernel(
    const float* __restrict__ x, const float* __restrict__ y,
    unsigned* __restrict__ wsu, float* __restrict__ partials,
    float* __restrict__ out) {
  __shared__ unsigned sh_cand[CAND_MAX];
  __shared__ unsigned sh_redM[4];
  __shared__ unsigned sh_redC[4];
  __shared__ unsigned sh_cnt;
  __shared__ unsigned sh_e11;
  __shared__ unsigned sh_last;
  __shared__ float sh_wl[4][10];
  __shared__ float sh_fin[4];

  const int tid = threadIdx.x;
  const int lane = tid & 63;
  const int wid = tid >> 6;
  const int b = blockIdx.x;
  const long long base = (long long)b * CC;

  // ---- 1. stream row (coalesced float4, per-row alignment fixup), encode ----
  unsigned enc[NSLOT];
  const int soff = (4 - (b & 3)) & 3;          // (b*9605 + soff) % 4 == 0
  const int ngroups = (CC - soff) >> 2;        // 2400 or 2401
  const int tailn = CC - soff - (ngroups << 2);
  const int m_extra = soff + tailn;            // <= 6 scalar leftovers
  const float4* vp = (const float4*)(x + base + soff);  // 16B aligned
#pragma unroll
  for (int i = 0; i < 9; ++i) {                // g <= 2303 < 2400: no bound
    float4 v = vp[tid + (i << 8)];
    enc[4 * i + 0] = enc_f(v.x);
    enc[4 * i + 1] = enc_f(v.y);
    enc[4 * i + 2] = enc_f(v.z);
    enc[4 * i + 3] = enc_f(v.w);
  }
  {
    int g = tid + (9 << 8);
    if (g < ngroups) {
      float4 v = vp[g];
      enc[36] = enc_f(v.x); enc[37] = enc_f(v.y);
      enc[38] = enc_f(v.z); enc[39] = enc_f(v.w);
    } else {
      enc[36] = 0u; enc[37] = 0u; enc[38] = 0u; enc[39] = 0u;
    }
  }
  if (tid < m_extra) {
    int col = (tid < soff) ? tid : (soff + (ngroups << 2) + (tid - soff));
    enc[40] = enc_f(x[base + col]);
  } else {
    enc[40] = 0u;
  }

  // ---- 2. whitelist gather accumulate (issue scattered loads EARLY so the
  //         latency overlaps the selection phase below) ----
  const unsigned nu = wsu[0];
  const unsigned* ents = wsu + 4;
  float lm[8];
#pragma unroll
  for (int l = 0; l < 8; ++l) lm[l] = NEGF;
  unsigned pmask = 0u;  // bits0-7: label present; bits8-15: label has positive
  for (unsigned e = tid; e < nu; e += 256u) {
    unsigned ent = ents[e];
    unsigned ccol = ent >> 8;
    unsigned mk = ent & 255u;
    float xv = x[base + (long long)ccol];
    float yv = y[base + (long long)ccol];
    pmask |= mk;
    if (yv > 0.0f) pmask |= (mk << 8);
#pragma unroll
    for (int l = 0; l < 8; ++l)
      if ((mk >> l) & 1u) lm[l] = fmaxf(lm[l], xv);
  }

  // ---- 3. block max of enc ----
  unsigned mx = 0u;
#pragma unroll
  for (int i = 0; i < NSLOT; ++i) mx = max(mx, enc[i]);
#pragma unroll
  for (int off = 32; off >= 1; off >>= 1) mx = max(mx, __shfl_xor(mx, off, 64));
  if (lane == 0) sh_redM[wid] = mx;
  if (tid == 0) { sh_cnt = 0u; }
  __syncthreads();
  const unsigned Emax =
      max(max(sh_redM[0], sh_redM[1]), max(sh_redM[2], sh_redM[3]));

  // block count of enc >= T (uniform result; 2 barriers incl reuse guard)
  auto blk_count = [&](unsigned T) -> unsigned {
    unsigned cnt = 0u;
#pragma unroll
    for (int i = 0; i < NSLOT; ++i) cnt += (enc[i] >= T) ? 1u : 0u;
#pragma unroll
    for (int off = 32; off >= 1; off >>= 1) cnt += __shfl_xor(cnt, off, 64);
    __syncthreads();
    if (lane == 0) sh_redC[wid] = cnt;
    __syncthreads();
    return sh_redC[0] + sh_redC[1] + sh_redC[2] + sh_redC[3];
  };

  // ---- 4. find window [lo, ...] holding rank 11 (typ. 1 probe) ----
  unsigned E11 = 0u;
  bool done = false;
  unsigned lo = (Emax > (1u << 23)) ? (Emax - (1u << 23)) : 1u;
  unsigned hi = Emax + 1u;
  unsigned c = blk_count(lo);
  while (c < 11u && lo > 1u) {
    hi = lo;
    lo = (lo > (1u << 23)) ? (lo - (1u << 23)) : 1u;
    c = blk_count(lo);
  }
  while (c > CAND_MAX) {  // rare: shrink by bisection (tie-collapse => exact)
    if (hi - lo <= 1u) { E11 = lo; done = true; break; }
    unsigned mid = lo + ((hi - lo) >> 1);
    unsigned cm = blk_count(mid);
    if (cm >= 11u) { lo = mid; c = cm; } else { hi = mid; }
  }

  // ---- 5. compact candidates to LDS, rank by broadcast counting ----
  if (!done) {
#pragma unroll
    for (int i = 0; i < NSLOT; ++i) {
      bool pr = (enc[i] >= lo);
      unsigned long long bal = __ballot(pr);
      if (bal) {
        unsigned wcnt = (unsigned)__popcll(bal);
        unsigned basep = 0u;
        if (lane == 0) basep = atomicAdd(&sh_cnt, wcnt);
        basep = __shfl(basep, 0, 64);
        if (pr) {
          unsigned posn = basep + (unsigned)__popcll(bal & ((1ull << lane) - 1ull));
          sh_cand[posn] = enc[i];
        }
      }
    }
    __syncthreads();
    // exactly one distinct value v satisfies: |{>v}| <= 10 and |{>=v}| >= 11
    unsigned e0 = (tid < (int)c) ? sh_cand[tid] : 0u;
    unsigned e1 = (tid + 256 < (int)c) ? sh_cand[tid + 256] : 0u;
    unsigned gt0 = 0u, ge0 = 0u, gt1 = 0u, ge1 = 0u;
    for (unsigned j = 0; j < c; ++j) {
      unsigned v = sh_cand[j];  // same addr all lanes: LDS broadcast, free
      gt0 += (v > e0); ge0 += (v >= e0);
      gt1 += (v > e1); ge1 += (v >= e1);
    }
    if (tid < (int)c && gt0 <= 10u && ge0 >= 11u) sh_e11 = e0;
    if (tid + 256 < (int)c && gt1 <= 10u && ge1 >= 11u) sh_e11 = e1;
    __syncthreads();
    E11 = sh_e11;
  }

  // ---- 6. reduce gather results across block ----
#pragma unroll
  for (int off = 32; off >= 1; off >>= 1) {
    pmask |= __shfl_xor(pmask, off, 64);
#pragma unroll
    for (int l = 0; l < 8; ++l) lm[l] = fmaxf(lm[l], __shfl_xor(lm[l], off, 64));
  }
  if (lane == 0) {
#pragma unroll
    for (int l = 0; l < 8; ++l) sh_wl[wid][l] = lm[l];
    sh_wl[wid][8] = __uint_as_float(pmask);
  }
  __syncthreads();

  // ---- 7. epilogue on thread 0: per-row value + done-count ----
  if (tid == 0) {
    float LM[8];
    unsigned PM = 0u;
#pragma unroll
    for (int l = 0; l < 8; ++l) LM[l] = NEGF;
    for (int w = 0; w < 4; ++w) {
#pragma unroll
      for (int l = 0; l < 8; ++l) LM[l] = fmaxf(LM[l], sh_wl[w][l]);
      PM |= __float_as_uint(sh_wl[w][8]);
    }
    unsigned PR = PM & 255u, PO = (PM >> 8) & 255u;
    float thres = fmaxf(sigm(dec_u(E11)), 0.5f);
    float cmax = NEGF, imax = NEGF, umax = NEGF;
#pragma unroll
    for (int l = 0; l < 8; ++l) {
      if ((PR >> l) & 1u) {
        float ml = sigm(LM[l]);
        umax = fmaxf(umax, ml);
        if ((PO >> l) & 1u) cmax = fmaxf(cmax, ml);
        else imax = fmaxf(imax, ml);
      } else if (!((PO >> l) & 1u)) {
        imax = fmaxf(imax, NEGF);
      }
    }
    bool anyc = (PO != 0u);
    bool anyi = (PO != 255u);  // L == 8 labels always exist
    float x1 = anyc ? cmax : thres;
    float x2 = anyc ? (anyi ? fmaxf(imax, thres) : thres)
                    : ((nu > 0u) ? umax : NEGF);
    float coef = anyc ? 1.0f : 0.5f;
    float dd = x2 - x1 + 0.1f;
    float rank = ((dd > 0.0f) ? 2.0f : 1.0f) * sigm(10.0f * dd);
    partials[b] = coef * rank;
    __threadfence();
    unsigned old = atomicAdd(&wsu[2], 1u);
    sh_last = (old == (unsigned)(BB - 1)) ? 1u : 0u;
  }
  __syncthreads();

  // ---- 8. last block reduces partials -> out (replaces extra kernel) ----
  if (sh_last) {
    __threadfence();
    float s = 0.0f;
    for (int i = tid; i < BB; i += 256) s += partials[i];
#pragma unroll
    for (int off = 32; off >= 1; off >>= 1) s += __shfl_xor(s, off, 64);
    if (lane == 0) sh_fin[wid] = s;
    __syncthreads();
    if (tid == 0)
      out[0] = (sh_fin[0] + sh_fin[1] + sh_fin[2] + sh_fin[3]) * (1.0f / (float)BB);
  }
}

extern "C" void kernel_launch(void* const* d_in, const int* in_sizes, int n_in,
                              void* d_out, int out_size, void* d_ws,
                              size_t ws_size, hipStream_t stream) {
  const float* x = (const float*)d_in[0];
  const float* y = (const float*)d_in[1];
  // d_in[2] (y_neg) is faithfully ignored — it never affects the loss.
  const unsigned char* wl = (const unsigned char*)d_in[3];
  float* out = (float*)d_out;
  unsigned* wsu = (unsigned*)d_ws;
  float* partials = (float*)((char*)d_ws + WS_PARTIALS_OFF);

  hipMemsetAsync(d_ws, 0, 16, stream);  // zero wsu[0..3]
  wl_sniff<<<64, 256, 0, stream>>>((const unsigned*)wl, wsu);
  wl_compact<<<(CC + 255) / 256, 256, 0, stream>>>(wl, wsu);
  loss_kernel<<<BB, 256, 0, stream>>>(x, y, wsu, partials, out);
}